// Round 4
// baseline (252.702 us; speedup 1.0000x reference)
//
#include <hip/hip_runtime.h>
#include <hip/hip_bf16.h>
#include <stdint.h>

typedef __attribute__((ext_vector_type(8))) short bf16x8;
typedef __attribute__((ext_vector_type(4))) float f32x4;
typedef __attribute__((ext_vector_type(4))) unsigned short us4;

#define AS1C(p) ((const __attribute__((address_space(1))) void*)(p))
#define AS3(p)  ((__attribute__((address_space(3))) void*)(p))

static __device__ __forceinline__ unsigned short f2b(float f) {
  union { __hip_bfloat16 h; unsigned short u; } cv;
  cv.h = __float2bfloat16(f);
  return cv.u;
}

// ---------------------------------------------------------------------------
// Conversions
// ---------------------------------------------------------------------------
__global__ __launch_bounds__(256) void conv_x_kernel(const float* __restrict__ x,
                                                     unsigned short* __restrict__ xb,
                                                     int n4) {
  int i = blockIdx.x * 256 + threadIdx.x;
  if (i >= n4) return;
  float4 v = ((const float4*)x)[i];
  us4 r = { f2b(v.x), f2b(v.y), f2b(v.z), f2b(v.w) };
  *(us4*)&xb[(size_t)i * 4] = r;
}

// WqkvT[n][d] = W_{which}[h][d][c],  n = which*1024 + h*64 + c
__global__ __launch_bounds__(256) void conv_wqkv_kernel(const float* __restrict__ Wq,
                                                        const float* __restrict__ Wk,
                                                        const float* __restrict__ Wv,
                                                        unsigned short* __restrict__ WqkvT) {
  int bid = blockIdx.x;          // 3*16*16 = 768 blocks
  int which = bid >> 8;
  int h  = (bid >> 4) & 15;
  int dt = bid & 15;
  const float* W = (which == 0) ? Wq : (which == 1 ? Wk : Wv);
  __shared__ float tile[64][65];
  const int t = threadIdx.x;
  const int c  = t & 63;
  const int r0 = t >> 6;         // 0..3
  const float* src = W + (size_t)h * 65536 + (size_t)dt * 64 * 64;
#pragma unroll
  for (int it = 0; it < 16; ++it) {
    int r = r0 + it * 4;
    tile[r][c] = src[r * 64 + c];     // tile[d_local][c_local]
  }
  __syncthreads();
  const size_t n0 = (size_t)which * 1024 + h * 64;
  const int d0 = dt * 64;
#pragma unroll
  for (int it = 0; it < 16; ++it) {
    int cc = r0 + it * 4;             // c_local (output row)
    WqkvT[(n0 + cc) * 1024 + d0 + c] = f2b(tile[c][cc]);
  }
}

// WoT[n][k] = Wo[k][n]
__global__ __launch_bounds__(256) void conv_wo_kernel(const float* __restrict__ Wo,
                                                      unsigned short* __restrict__ WoT) {
  int kt = blockIdx.x >> 4, nt = blockIdx.x & 15;   // 256 blocks
  __shared__ float tile[64][65];
  const int t = threadIdx.x;
  const int c  = t & 63;
  const int r0 = t >> 6;
  const float* src = Wo + (size_t)(kt * 64) * 1024 + nt * 64;
#pragma unroll
  for (int it = 0; it < 16; ++it) {
    int r = r0 + it * 4;
    tile[r][c] = src[(size_t)r * 1024 + c];   // tile[k_local][n_local]
  }
  __syncthreads();
#pragma unroll
  for (int it = 0; it < 16; ++it) {
    int cc = r0 + it * 4;                     // n_local (output row)
    WoT[((size_t)nt * 64 + cc) * 1024 + kt * 64 + c] = f2b(tile[c][cc]);
  }
}

// ---------------------------------------------------------------------------
// GEMM 1: C[8192][3072] = x_bf16 [8192][1024] * WqkvT[3072][1024]^T
// epilogue: Q pre-scaled by (1/8)*log2(e) (exp2-folded softmax); K straight;
// V written TRANSPOSED into Vt[B*H][dk][S] (us4 packed stores, j spans s).
// ---------------------------------------------------------------------------
__global__ __launch_bounds__(256) void gemm_qkv_kernel(
    const unsigned short* __restrict__ A,
    const unsigned short* __restrict__ Bt,
    unsigned short* __restrict__ Q,
    unsigned short* __restrict__ Ko,
    unsigned short* __restrict__ Vt) {
  __shared__ __align__(16) unsigned short sA[128 * 32];
  __shared__ __align__(16) unsigned short sB[128 * 32];
  const int tid  = threadIdx.x;
  const int lane = tid & 63;
  const int wid  = tid >> 6;
  const int wr = wid >> 1, wc = wid & 1;
  const int brow = blockIdx.y * 128;
  const int bcol = blockIdx.x * 128;
  const int K = 1024;

  f32x4 acc[4][4] = {};

  const int r4 = tid >> 2;          // 0..63
  const int c8 = (tid & 3) * 8;
  const unsigned short* ga = A  + (size_t)(brow + r4) * K + c8;
  const unsigned short* gb = Bt + (size_t)(bcol + r4) * K + c8;
  unsigned short* lAw = sA + wid * 512;   // wave-uniform LDS base (lane*16B added by HW)
  unsigned short* lBw = sB + wid * 512;

  for (int kb = 0; kb < K; kb += 32) {
    if (kb) __syncthreads();
    __builtin_amdgcn_global_load_lds(AS1C(ga + kb),            AS3(lAw),        16, 0, 0);
    __builtin_amdgcn_global_load_lds(AS1C(ga + 64 * K + kb),   AS3(lAw + 2048), 16, 0, 0);
    __builtin_amdgcn_global_load_lds(AS1C(gb + kb),            AS3(lBw),        16, 0, 0);
    __builtin_amdgcn_global_load_lds(AS1C(gb + 64 * K + kb),   AS3(lBw + 2048), 16, 0, 0);
    __syncthreads();

    bf16x8 af[4], bfr[4];
#pragma unroll
    for (int mi = 0; mi < 4; ++mi)
      af[mi] = *(const bf16x8*)&sA[(wr * 64 + mi * 16 + (lane & 15)) * 32 + (lane >> 4) * 8];
#pragma unroll
    for (int ni = 0; ni < 4; ++ni)
      bfr[ni] = *(const bf16x8*)&sB[(wc * 64 + ni * 16 + (lane & 15)) * 32 + (lane >> 4) * 8];
#pragma unroll
    for (int mi = 0; mi < 4; ++mi)
#pragma unroll
      for (int ni = 0; ni < 4; ++ni)
        acc[mi][ni] = __builtin_amdgcn_mfma_f32_16x16x32_bf16(af[mi], bfr[ni], acc[mi][ni], 0, 0, 0);
  }

#pragma unroll
  for (int mi = 0; mi < 4; ++mi) {
    int row0 = brow + wr * 64 + mi * 16 + (lane >> 4) * 4;
    int b = row0 >> 11, s0 = row0 & 2047;
#pragma unroll
    for (int ni = 0; ni < 4; ++ni) {
      int col = bcol + wc * 64 + ni * 16 + (lane & 15);
      int which = col >> 10;      // block-uniform
      int h  = (col >> 6) & 15;
      int kk = col & 63;
      if (which == 2) {
        us4 pk = { f2b(acc[mi][ni][0]), f2b(acc[mi][ni][1]),
                   f2b(acc[mi][ni][2]), f2b(acc[mi][ni][3]) };
        *(us4*)&Vt[((size_t)(b * 16 + h) * 64 + kk) * 2048 + s0] = pk;
      } else {
        unsigned short* dst = (which == 0) ? Q : Ko;
        // Q: fold 1/sqrt(dk) * log2(e) so softmax uses raw v_exp (2^x)
        float scl = (which == 0) ? 0.18033688f : 1.0f;
#pragma unroll
        for (int j = 0; j < 4; ++j)
          dst[((size_t)(b * 16 + h) * 2048 + (s0 + j)) * 64 + kk] = f2b(acc[mi][ni][j] * scl);
      }
    }
  }
}

// ---------------------------------------------------------------------------
// GEMM 2: out[8192][1024] (fp32) = O_bf16 [8192][1024] * WoT[1024][1024]^T
// ---------------------------------------------------------------------------
__global__ __launch_bounds__(256) void gemm_out_kernel(
    const unsigned short* __restrict__ A,
    const unsigned short* __restrict__ Bt,
    float* __restrict__ out) {
  __shared__ __align__(16) unsigned short sA[128 * 32];
  __shared__ __align__(16) unsigned short sB[128 * 32];
  const int tid  = threadIdx.x;
  const int lane = tid & 63;
  const int wid  = tid >> 6;
  const int wr = wid >> 1, wc = wid & 1;
  const int brow = blockIdx.y * 128;
  const int bcol = blockIdx.x * 128;
  const int K = 1024;

  f32x4 acc[4][4] = {};

  const int r4 = tid >> 2;
  const int c8 = (tid & 3) * 8;
  const unsigned short* ga = A  + (size_t)(brow + r4) * K + c8;
  const unsigned short* gb = Bt + (size_t)(bcol + r4) * K + c8;
  unsigned short* lAw = sA + wid * 512;
  unsigned short* lBw = sB + wid * 512;

  for (int kb = 0; kb < K; kb += 32) {
    if (kb) __syncthreads();
    __builtin_amdgcn_global_load_lds(AS1C(ga + kb),          AS3(lAw),        16, 0, 0);
    __builtin_amdgcn_global_load_lds(AS1C(ga + 64 * K + kb), AS3(lAw + 2048), 16, 0, 0);
    __builtin_amdgcn_global_load_lds(AS1C(gb + kb),          AS3(lBw),        16, 0, 0);
    __builtin_amdgcn_global_load_lds(AS1C(gb + 64 * K + kb), AS3(lBw + 2048), 16, 0, 0);
    __syncthreads();

    bf16x8 af[4], bfr[4];
#pragma unroll
    for (int mi = 0; mi < 4; ++mi)
      af[mi] = *(const bf16x8*)&sA[(wr * 64 + mi * 16 + (lane & 15)) * 32 + (lane >> 4) * 8];
#pragma unroll
    for (int ni = 0; ni < 4; ++ni)
      bfr[ni] = *(const bf16x8*)&sB[(wc * 64 + ni * 16 + (lane & 15)) * 32 + (lane >> 4) * 8];
#pragma unroll
    for (int mi = 0; mi < 4; ++mi)
#pragma unroll
      for (int ni = 0; ni < 4; ++ni)
        acc[mi][ni] = __builtin_amdgcn_mfma_f32_16x16x32_bf16(af[mi], bfr[ni], acc[mi][ni], 0, 0, 0);
  }

#pragma unroll
  for (int mi = 0; mi < 4; ++mi) {
    int row0 = brow + wr * 64 + mi * 16 + (lane >> 4) * 4;
#pragma unroll
    for (int ni = 0; ni < 4; ++ni) {
      int col = bcol + wc * 64 + ni * 16 + (lane & 15);
#pragma unroll
      for (int j = 0; j < 4; ++j)
        out[(size_t)(row0 + j) * 1024 + col] = acc[mi][ni][j];
    }
  }
}

// ---------------------------------------------------------------------------
// Flash attention, swapped QK^T + defer-max (T13) + exp2-folded softmax.
// grid 1024 blocks, XCD-relabeled so 8 consecutive bh live on one XCD
// (per-XCD K/V working set = 8 x 512KB = 4MB = one L2).
// Q,K: [64][2048][64] bf16 (Q pre-scaled by 0.125*log2e).  Vt: [64][64][2048].
// O: [4][2048][1024] bf16.
// mfma(K,Q) -> C col = q = lane&15, row = key = (lane>>4)*4+reg.
// ---------------------------------------------------------------------------
__global__ __launch_bounds__(256) void attn_kernel(
    const unsigned short* __restrict__ Q,
    const unsigned short* __restrict__ K,
    const unsigned short* __restrict__ Vt,
    unsigned short* __restrict__ O) {
  __shared__ __align__(16) unsigned short sK[64 * 72];     // [key][dk] pad 72
  __shared__ __align__(16) unsigned short sVt[64 * 72];    // [dk][key] pad 72
  __shared__ __align__(16) unsigned short sP[8][16 * 72];  // [w*2+mi][q][key] pad 72

  const int tid = threadIdx.x, lane = tid & 63, w = tid >> 6;
  const int l15 = lane & 15, hi = lane >> 4;
  // bijective XCD relabel: dispatch n -> xcd = n&7; 8 bh per XCD, 16 q-blocks each
  const int n = blockIdx.x + (blockIdx.y << 4);
  const int bh = (n & 7) * 8 + ((n >> 3) >> 4);
  const int qx = (n >> 3) & 15;
  const int qb = qx * 128;
  const unsigned short* Qp  = Q  + (size_t)bh * 131072;
  const unsigned short* Kp  = K  + (size_t)bh * 131072;
  const unsigned short* Vtp = Vt + (size_t)bh * 131072;

  bf16x8 qf[2][2];
#pragma unroll
  for (int mi = 0; mi < 2; ++mi) {
    int qrow = qb + w * 32 + mi * 16 + l15;
    qf[mi][0] = *(const bf16x8*)&Qp[(size_t)qrow * 64 + hi * 8];
    qf[mi][1] = *(const bf16x8*)&Qp[(size_t)qrow * 64 + 32 + hi * 8];
  }

  f32x4 o[2][4] = {};
  float m_[2] = { 0.f, 0.f };      // defer-max: start at 0 (scores log2-scaled)
  float l_[2] = { 0.f, 0.f };

  const int sr  = tid >> 3;        // 0..31
  const int sc8 = (tid & 7) * 8;

  // staging pointers (strength-reduced; tile strides 4096 / 64)
  const unsigned short* kptr = Kp  + (size_t)sr * 64 + sc8;
  const unsigned short* vptr = Vtp + (size_t)sr * 2048 + sc8;

  // prologue: tile 0 into regs (async-stage: issue early, write late)
  bf16x8 rk0 = *(const bf16x8*)kptr;
  bf16x8 rk1 = *(const bf16x8*)(kptr + 2048);
  bf16x8 rv0 = *(const bf16x8*)vptr;
  bf16x8 rv1 = *(const bf16x8*)(vptr + 65536);

  for (int kt = 0; kt < 32; ++kt) {
    __syncthreads();               // previous tile's compute done
    *(bf16x8*)&sK[sr * 72 + sc8]         = rk0;
    *(bf16x8*)&sK[(sr + 32) * 72 + sc8]  = rk1;
    *(bf16x8*)&sVt[sr * 72 + sc8]        = rv0;
    *(bf16x8*)&sVt[(sr + 32) * 72 + sc8] = rv1;
    __syncthreads();               // LDS ready

    if (kt < 31) {                 // issue next tile's loads; land next iter
      kptr += 4096; vptr += 64;
      rk0 = *(const bf16x8*)kptr;
      rk1 = *(const bf16x8*)(kptr + 2048);
      rv0 = *(const bf16x8*)vptr;
      rv1 = *(const bf16x8*)(vptr + 65536);
    }

#pragma unroll
    for (int mi = 0; mi < 2; ++mi) {
      // S^T = K Q^T : sc[ni][r] = S[key=16ni+4hi+r][q=l15]  (log2-units)
      f32x4 sc[4] = {};
      __builtin_amdgcn_s_setprio(1);
#pragma unroll
      for (int ni = 0; ni < 4; ++ni) {
        bf16x8 kf0 = *(const bf16x8*)&sK[(ni * 16 + l15) * 72 + hi * 8];
        bf16x8 kf1 = *(const bf16x8*)&sK[(ni * 16 + l15) * 72 + 32 + hi * 8];
        sc[ni] = __builtin_amdgcn_mfma_f32_16x16x32_bf16(kf0, qf[mi][0], sc[ni], 0, 0, 0);
        sc[ni] = __builtin_amdgcn_mfma_f32_16x16x32_bf16(kf1, qf[mi][1], sc[ni], 0, 0, 0);
      }
      __builtin_amdgcn_s_setprio(0);

      // per-q (= lane) tile max, for the defer-max guard
      float mx0 = fmaxf(fmaxf(sc[0][0], sc[0][1]), fmaxf(sc[0][2], sc[0][3]));
      float mx1 = fmaxf(fmaxf(sc[1][0], sc[1][1]), fmaxf(sc[1][2], sc[1][3]));
      float mx2 = fmaxf(fmaxf(sc[2][0], sc[2][1]), fmaxf(sc[2][2], sc[2][3]));
      float mx3 = fmaxf(fmaxf(sc[3][0], sc[3][1]), fmaxf(sc[3][2], sc[3][3]));
      float pmax = fmaxf(fmaxf(mx0, mx1), fmaxf(mx2, mx3));
      pmax = fmaxf(pmax, __shfl_xor(pmax, 16));
      pmax = fmaxf(pmax, __shfl_xor(pmax, 32));

      // T13: rescale only if P would exceed 2^8 (never fires on sane data)
      if (!__all(pmax - m_[mi] <= 8.0f)) {
        float mnew  = fmaxf(m_[mi], pmax);
        float alpha = exp2f(m_[mi] - mnew);
        l_[mi] *= alpha;
#pragma unroll
        for (int j = 0; j < 4; ++j) {
          float aj = __shfl(alpha, hi * 4 + j);
#pragma unroll
          for (int ni = 0; ni < 4; ++ni) o[mi][ni][j] *= aj;
        }
        m_[mi] = mnew;
      }

      const float mcur = m_[mi];
      f32x4 sum4 = {};
#pragma unroll
      for (int ni = 0; ni < 4; ++ni)
#pragma unroll
        for (int r = 0; r < 4; ++r) {
          float p = exp2f(sc[ni][r] - mcur);
          sc[ni][r] = p;
          sum4[r] += p;
        }
      float rsum = (sum4[0] + sum4[1]) + (sum4[2] + sum4[3]);
      rsum += __shfl_xor(rsum, 16);
      rsum += __shfl_xor(rsum, 32);
      l_[mi] += rsum;

      // P -> per-wave LDS [q=l15][key], packed us4 (4 consecutive keys)
      unsigned short* pb = &sP[w * 2 + mi][l15 * 72];
#pragma unroll
      for (int ni = 0; ni < 4; ++ni) {
        us4 pk = { f2b(sc[ni][0]), f2b(sc[ni][1]), f2b(sc[ni][2]), f2b(sc[ni][3]) };
        *(us4*)&pb[ni * 16 + hi * 4] = pk;
      }
    }

    // O += P V
    bf16x8 pa[2][2];
#pragma unroll
    for (int mi = 0; mi < 2; ++mi) {
      pa[mi][0] = *(const bf16x8*)&sP[w * 2 + mi][l15 * 72 + hi * 8];
      pa[mi][1] = *(const bf16x8*)&sP[w * 2 + mi][l15 * 72 + 32 + hi * 8];
    }
    __builtin_amdgcn_s_setprio(1);
#pragma unroll
    for (int ni = 0; ni < 4; ++ni) {
      bf16x8 vf0 = *(const bf16x8*)&sVt[(ni * 16 + l15) * 72 + hi * 8];
      bf16x8 vf1 = *(const bf16x8*)&sVt[(ni * 16 + l15) * 72 + 32 + hi * 8];
#pragma unroll
      for (int mi = 0; mi < 2; ++mi) {
        o[mi][ni] = __builtin_amdgcn_mfma_f32_16x16x32_bf16(pa[mi][0], vf0, o[mi][ni], 0, 0, 0);
        o[mi][ni] = __builtin_amdgcn_mfma_f32_16x16x32_bf16(pa[mi][1], vf1, o[mi][ni], 0, 0, 0);
      }
    }
    __builtin_amdgcn_s_setprio(0);
  }

  const int b = bh >> 4, h = bh & 15;
#pragma unroll
  for (int mi = 0; mi < 2; ++mi) {
    float linv = 1.0f / l_[mi];
#pragma unroll
    for (int j = 0; j < 4; ++j) {
      float inv = __shfl(linv, hi * 4 + j);
      int row = qb + w * 32 + mi * 16 + hi * 4 + j;
#pragma unroll
      for (int ni = 0; ni < 4; ++ni)
        O[((size_t)b * 2048 + row) * 1024 + h * 64 + ni * 16 + l15] = f2b(o[mi][ni][j] * inv);
    }
  }
}

// ---------------------------------------------------------------------------
extern "C" void kernel_launch(void* const* d_in, const int* in_sizes, int n_in,
                              void* d_out, int out_size, void* d_ws, size_t ws_size,
                              hipStream_t stream) {
  const float* x  = (const float*)d_in[0];
  const float* Wq = (const float*)d_in[1];
  const float* Wk = (const float*)d_in[2];
  const float* Wv = (const float*)d_in[3];
  const float* Wo = (const float*)d_in[4];
  float* out = (float*)d_out;

  char* w = (char*)d_ws;
  unsigned short* xb   = (unsigned short*)(w);                       // 16 MB
  unsigned short* wqkv = (unsigned short*)(w + 16777216);            //  6 MB
  unsigned short* wo   = (unsigned short*)(w + 23068672);            //  2 MB
  unsigned short* Qb   = (unsigned short*)(w + 25165824);            // 16 MB
  unsigned short* Kb   = (unsigned short*)(w + 41943040);            // 16 MB
  unsigned short* Vtb  = (unsigned short*)(w + 58720256);            // 16 MB (V transposed)
  unsigned short* Ob   = (unsigned short*)(w + 75497472);            // 16 MB

  conv_x_kernel<<<8192, 256, 0, stream>>>(x, xb, 2097152);
  conv_wqkv_kernel<<<768, 256, 0, stream>>>(Wq, Wk, Wv, wqkv);
  conv_wo_kernel<<<256, 256, 0, stream>>>(Wo, wo);
  gemm_qkv_kernel<<<dim3(24, 64), 256, 0, stream>>>(xb, wqkv, Qb, Kb, Vtb);
  attn_kernel<<<dim3(16, 64), 256, 0, stream>>>(Qb, Kb, Vtb, Ob);
  gemm_out_kernel<<<dim3(8, 64), 256, 0, stream>>>(Ob, wo, out);
}

// Round 5
// 230.531 us; speedup vs baseline: 1.0962x; 1.0962x over previous
//
#include <hip/hip_runtime.h>
#include <hip/hip_bf16.h>
#include <stdint.h>

typedef __attribute__((ext_vector_type(8))) short bf16x8;
typedef __attribute__((ext_vector_type(4))) float f32x4;
typedef __attribute__((ext_vector_type(4))) unsigned short us4;

#define AS1C(p) ((const __attribute__((address_space(1))) void*)(p))
#define AS3(p)  ((__attribute__((address_space(3))) void*)(p))

// raw v_exp_f32 (2^x). exp2f (libm) lowers to OCML with denormal fixup — slow.
#if __has_builtin(__builtin_amdgcn_exp2f)
#define EXP2(x) __builtin_amdgcn_exp2f(x)
#else
#define EXP2(x) __expf((x) * 0.69314718f)
#endif

static __device__ __forceinline__ unsigned short f2b(float f) {
  union { __hip_bfloat16 h; unsigned short u; } cv;
  cv.h = __float2bfloat16(f);
  return cv.u;
}

// ---------------------------------------------------------------------------
// Conversions
// ---------------------------------------------------------------------------
__global__ __launch_bounds__(256) void conv_x_kernel(const float* __restrict__ x,
                                                     unsigned short* __restrict__ xb,
                                                     int n4) {
  int i = blockIdx.x * 256 + threadIdx.x;
  if (i >= n4) return;
  float4 v = ((const float4*)x)[i];
  us4 r = { f2b(v.x), f2b(v.y), f2b(v.z), f2b(v.w) };
  *(us4*)&xb[(size_t)i * 4] = r;
}

// WqkvT[n][d] = W_{which}[h][d][c],  n = which*1024 + h*64 + c
__global__ __launch_bounds__(256) void conv_wqkv_kernel(const float* __restrict__ Wq,
                                                        const float* __restrict__ Wk,
                                                        const float* __restrict__ Wv,
                                                        unsigned short* __restrict__ WqkvT) {
  int bid = blockIdx.x;          // 3*16*16 = 768 blocks
  int which = bid >> 8;
  int h  = (bid >> 4) & 15;
  int dt = bid & 15;
  const float* W = (which == 0) ? Wq : (which == 1 ? Wk : Wv);
  __shared__ float tile[64][65];
  const int t = threadIdx.x;
  const int c  = t & 63;
  const int r0 = t >> 6;         // 0..3
  const float* src = W + (size_t)h * 65536 + (size_t)dt * 64 * 64;
#pragma unroll
  for (int it = 0; it < 16; ++it) {
    int r = r0 + it * 4;
    tile[r][c] = src[r * 64 + c];     // tile[d_local][c_local]
  }
  __syncthreads();
  const size_t n0 = (size_t)which * 1024 + h * 64;
  const int d0 = dt * 64;
#pragma unroll
  for (int it = 0; it < 16; ++it) {
    int cc = r0 + it * 4;             // c_local (output row)
    WqkvT[(n0 + cc) * 1024 + d0 + c] = f2b(tile[c][cc]);
  }
}

// WoT[n][k] = Wo[k][n]
__global__ __launch_bounds__(256) void conv_wo_kernel(const float* __restrict__ Wo,
                                                      unsigned short* __restrict__ WoT) {
  int kt = blockIdx.x >> 4, nt = blockIdx.x & 15;   // 256 blocks
  __shared__ float tile[64][65];
  const int t = threadIdx.x;
  const int c  = t & 63;
  const int r0 = t >> 6;
  const float* src = Wo + (size_t)(kt * 64) * 1024 + nt * 64;
#pragma unroll
  for (int it = 0; it < 16; ++it) {
    int r = r0 + it * 4;
    tile[r][c] = src[(size_t)r * 1024 + c];   // tile[k_local][n_local]
  }
  __syncthreads();
#pragma unroll
  for (int it = 0; it < 16; ++it) {
    int cc = r0 + it * 4;                     // n_local (output row)
    WoT[((size_t)nt * 64 + cc) * 1024 + kt * 64 + c] = f2b(tile[c][cc]);
  }
}

// ---------------------------------------------------------------------------
// GEMM 1: C[8192][3072] = x_bf16 [8192][1024] * WqkvT[3072][1024]^T
// epilogue: Q pre-scaled by (1/8)*log2(e) (exp2-folded softmax); K straight;
// V written TRANSPOSED into Vt[B*H][dk][S] (us4 packed stores, j spans s).
// ---------------------------------------------------------------------------
__global__ __launch_bounds__(256) void gemm_qkv_kernel(
    const unsigned short* __restrict__ A,
    const unsigned short* __restrict__ Bt,
    unsigned short* __restrict__ Q,
    unsigned short* __restrict__ Ko,
    unsigned short* __restrict__ Vt) {
  __shared__ __align__(16) unsigned short sA[128 * 32];
  __shared__ __align__(16) unsigned short sB[128 * 32];
  const int tid  = threadIdx.x;
  const int lane = tid & 63;
  const int wid  = tid >> 6;
  const int wr = wid >> 1, wc = wid & 1;
  const int brow = blockIdx.y * 128;
  const int bcol = blockIdx.x * 128;
  const int K = 1024;

  f32x4 acc[4][4] = {};

  const int r4 = tid >> 2;          // 0..63
  const int c8 = (tid & 3) * 8;
  const unsigned short* ga = A  + (size_t)(brow + r4) * K + c8;
  const unsigned short* gb = Bt + (size_t)(bcol + r4) * K + c8;
  unsigned short* lAw = sA + wid * 512;   // wave-uniform LDS base (lane*16B added by HW)
  unsigned short* lBw = sB + wid * 512;

  for (int kb = 0; kb < K; kb += 32) {
    if (kb) __syncthreads();
    __builtin_amdgcn_global_load_lds(AS1C(ga + kb),            AS3(lAw),        16, 0, 0);
    __builtin_amdgcn_global_load_lds(AS1C(ga + 64 * K + kb),   AS3(lAw + 2048), 16, 0, 0);
    __builtin_amdgcn_global_load_lds(AS1C(gb + kb),            AS3(lBw),        16, 0, 0);
    __builtin_amdgcn_global_load_lds(AS1C(gb + 64 * K + kb),   AS3(lBw + 2048), 16, 0, 0);
    __syncthreads();

    bf16x8 af[4], bfr[4];
#pragma unroll
    for (int mi = 0; mi < 4; ++mi)
      af[mi] = *(const bf16x8*)&sA[(wr * 64 + mi * 16 + (lane & 15)) * 32 + (lane >> 4) * 8];
#pragma unroll
    for (int ni = 0; ni < 4; ++ni)
      bfr[ni] = *(const bf16x8*)&sB[(wc * 64 + ni * 16 + (lane & 15)) * 32 + (lane >> 4) * 8];
#pragma unroll
    for (int mi = 0; mi < 4; ++mi)
#pragma unroll
      for (int ni = 0; ni < 4; ++ni)
        acc[mi][ni] = __builtin_amdgcn_mfma_f32_16x16x32_bf16(af[mi], bfr[ni], acc[mi][ni], 0, 0, 0);
  }

#pragma unroll
  for (int mi = 0; mi < 4; ++mi) {
    int row0 = brow + wr * 64 + mi * 16 + (lane >> 4) * 4;
    int b = row0 >> 11, s0 = row0 & 2047;
#pragma unroll
    for (int ni = 0; ni < 4; ++ni) {
      int col = bcol + wc * 64 + ni * 16 + (lane & 15);
      int which = col >> 10;      // block-uniform
      int h  = (col >> 6) & 15;
      int kk = col & 63;
      if (which == 2) {
        us4 pk = { f2b(acc[mi][ni][0]), f2b(acc[mi][ni][1]),
                   f2b(acc[mi][ni][2]), f2b(acc[mi][ni][3]) };
        *(us4*)&Vt[((size_t)(b * 16 + h) * 64 + kk) * 2048 + s0] = pk;
      } else {
        unsigned short* dst = (which == 0) ? Q : Ko;
        // Q: fold 1/sqrt(dk) * log2(e) so softmax uses raw v_exp (2^x)
        float scl = (which == 0) ? 0.18033688f : 1.0f;
#pragma unroll
        for (int j = 0; j < 4; ++j)
          dst[((size_t)(b * 16 + h) * 2048 + (s0 + j)) * 64 + kk] = f2b(acc[mi][ni][j] * scl);
      }
    }
  }
}

// ---------------------------------------------------------------------------
// GEMM 2: out[8192][1024] (fp32) = O_bf16 [8192][1024] * WoT[1024][1024]^T
// ---------------------------------------------------------------------------
__global__ __launch_bounds__(256) void gemm_out_kernel(
    const unsigned short* __restrict__ A,
    const unsigned short* __restrict__ Bt,
    float* __restrict__ out) {
  __shared__ __align__(16) unsigned short sA[128 * 32];
  __shared__ __align__(16) unsigned short sB[128 * 32];
  const int tid  = threadIdx.x;
  const int lane = tid & 63;
  const int wid  = tid >> 6;
  const int wr = wid >> 1, wc = wid & 1;
  const int brow = blockIdx.y * 128;
  const int bcol = blockIdx.x * 128;
  const int K = 1024;

  f32x4 acc[4][4] = {};

  const int r4 = tid >> 2;
  const int c8 = (tid & 3) * 8;
  const unsigned short* ga = A  + (size_t)(brow + r4) * K + c8;
  const unsigned short* gb = Bt + (size_t)(bcol + r4) * K + c8;
  unsigned short* lAw = sA + wid * 512;
  unsigned short* lBw = sB + wid * 512;

  for (int kb = 0; kb < K; kb += 32) {
    if (kb) __syncthreads();
    __builtin_amdgcn_global_load_lds(AS1C(ga + kb),          AS3(lAw),        16, 0, 0);
    __builtin_amdgcn_global_load_lds(AS1C(ga + 64 * K + kb), AS3(lAw + 2048), 16, 0, 0);
    __builtin_amdgcn_global_load_lds(AS1C(gb + kb),          AS3(lBw),        16, 0, 0);
    __builtin_amdgcn_global_load_lds(AS1C(gb + 64 * K + kb), AS3(lBw + 2048), 16, 0, 0);
    __syncthreads();

    bf16x8 af[4], bfr[4];
#pragma unroll
    for (int mi = 0; mi < 4; ++mi)
      af[mi] = *(const bf16x8*)&sA[(wr * 64 + mi * 16 + (lane & 15)) * 32 + (lane >> 4) * 8];
#pragma unroll
    for (int ni = 0; ni < 4; ++ni)
      bfr[ni] = *(const bf16x8*)&sB[(wc * 64 + ni * 16 + (lane & 15)) * 32 + (lane >> 4) * 8];
#pragma unroll
    for (int mi = 0; mi < 4; ++mi)
#pragma unroll
      for (int ni = 0; ni < 4; ++ni)
        acc[mi][ni] = __builtin_amdgcn_mfma_f32_16x16x32_bf16(af[mi], bfr[ni], acc[mi][ni], 0, 0, 0);
  }

#pragma unroll
  for (int mi = 0; mi < 4; ++mi) {
    int row0 = brow + wr * 64 + mi * 16 + (lane >> 4) * 4;
#pragma unroll
    for (int ni = 0; ni < 4; ++ni) {
      int col = bcol + wc * 64 + ni * 16 + (lane & 15);
#pragma unroll
      for (int j = 0; j < 4; ++j)
        out[(size_t)(row0 + j) * 1024 + col] = acc[mi][ni][j];
    }
  }
}

// ---------------------------------------------------------------------------
// Flash attention, swapped QK^T + defer-max (T13) + exp2-folded softmax.
// grid 1024 blocks, XCD-relabeled so 8 consecutive bh live on one XCD
// (per-XCD K/V working set = 8 x 512KB = 4MB = one L2).
// Q,K: [64][2048][64] bf16 (Q pre-scaled by 0.125*log2e).  Vt: [64][64][2048].
// O: [4][2048][1024] bf16.
// mfma(K,Q) -> C col = q = lane&15, row = key = (lane>>4)*4+reg.
// ---------------------------------------------------------------------------
__global__ __launch_bounds__(256) void attn_kernel(
    const unsigned short* __restrict__ Q,
    const unsigned short* __restrict__ K,
    const unsigned short* __restrict__ Vt,
    unsigned short* __restrict__ O) {
  __shared__ __align__(16) unsigned short sK[64 * 72];     // [key][dk] pad 72
  __shared__ __align__(16) unsigned short sVt[64 * 72];    // [dk][key] pad 72
  __shared__ __align__(16) unsigned short sP[8][16 * 72];  // [w*2+mi][q][key] pad 72

  const int tid = threadIdx.x, lane = tid & 63, w = tid >> 6;
  const int l15 = lane & 15, hi = lane >> 4;
  // bijective XCD relabel: dispatch n -> xcd = n&7; 8 bh per XCD, 16 q-blocks each
  const int n = blockIdx.x + (blockIdx.y << 4);
  const int bh = (n & 7) * 8 + ((n >> 3) >> 4);
  const int qx = (n >> 3) & 15;
  const int qb = qx * 128;
  const unsigned short* Qp  = Q  + (size_t)bh * 131072;
  const unsigned short* Kp  = K  + (size_t)bh * 131072;
  const unsigned short* Vtp = Vt + (size_t)bh * 131072;

  bf16x8 qf[2][2];
#pragma unroll
  for (int mi = 0; mi < 2; ++mi) {
    int qrow = qb + w * 32 + mi * 16 + l15;
    qf[mi][0] = *(const bf16x8*)&Qp[(size_t)qrow * 64 + hi * 8];
    qf[mi][1] = *(const bf16x8*)&Qp[(size_t)qrow * 64 + 32 + hi * 8];
  }

  f32x4 o[2][4] = {};
  float m_[2] = { 0.f, 0.f };      // defer-max: start at 0 (scores log2-scaled)
  float l_[2] = { 0.f, 0.f };

  const int sr  = tid >> 3;        // 0..31
  const int sc8 = (tid & 7) * 8;

  // staging pointers (strength-reduced; tile strides 4096 / 64)
  const unsigned short* kptr = Kp  + (size_t)sr * 64 + sc8;
  const unsigned short* vptr = Vtp + (size_t)sr * 2048 + sc8;

  // prologue: tile 0 into regs (async-stage: issue early, write late)
  bf16x8 rk0 = *(const bf16x8*)kptr;
  bf16x8 rk1 = *(const bf16x8*)(kptr + 2048);
  bf16x8 rv0 = *(const bf16x8*)vptr;
  bf16x8 rv1 = *(const bf16x8*)(vptr + 65536);

  for (int kt = 0; kt < 32; ++kt) {
    __syncthreads();               // previous tile's compute done
    *(bf16x8*)&sK[sr * 72 + sc8]         = rk0;
    *(bf16x8*)&sK[(sr + 32) * 72 + sc8]  = rk1;
    *(bf16x8*)&sVt[sr * 72 + sc8]        = rv0;
    *(bf16x8*)&sVt[(sr + 32) * 72 + sc8] = rv1;
    __syncthreads();               // LDS ready

    if (kt < 31) {                 // issue next tile's loads; land next iter
      kptr += 4096; vptr += 64;
      rk0 = *(const bf16x8*)kptr;
      rk1 = *(const bf16x8*)(kptr + 2048);
      rv0 = *(const bf16x8*)vptr;
      rv1 = *(const bf16x8*)(vptr + 65536);
    }

#pragma unroll
    for (int mi = 0; mi < 2; ++mi) {
      // S^T = K Q^T : sc[ni][r] = S[key=16ni+4hi+r][q=l15]  (log2-units)
      f32x4 sc[4] = {};
      __builtin_amdgcn_s_setprio(1);
#pragma unroll
      for (int ni = 0; ni < 4; ++ni) {
        bf16x8 kf0 = *(const bf16x8*)&sK[(ni * 16 + l15) * 72 + hi * 8];
        bf16x8 kf1 = *(const bf16x8*)&sK[(ni * 16 + l15) * 72 + 32 + hi * 8];
        sc[ni] = __builtin_amdgcn_mfma_f32_16x16x32_bf16(kf0, qf[mi][0], sc[ni], 0, 0, 0);
        sc[ni] = __builtin_amdgcn_mfma_f32_16x16x32_bf16(kf1, qf[mi][1], sc[ni], 0, 0, 0);
      }
      __builtin_amdgcn_s_setprio(0);

      // per-q (= lane) tile max, for the defer-max guard
      float mx0 = fmaxf(fmaxf(sc[0][0], sc[0][1]), fmaxf(sc[0][2], sc[0][3]));
      float mx1 = fmaxf(fmaxf(sc[1][0], sc[1][1]), fmaxf(sc[1][2], sc[1][3]));
      float mx2 = fmaxf(fmaxf(sc[2][0], sc[2][1]), fmaxf(sc[2][2], sc[2][3]));
      float mx3 = fmaxf(fmaxf(sc[3][0], sc[3][1]), fmaxf(sc[3][2], sc[3][3]));
      float pmax = fmaxf(fmaxf(mx0, mx1), fmaxf(mx2, mx3));
      pmax = fmaxf(pmax, __shfl_xor(pmax, 16));
      pmax = fmaxf(pmax, __shfl_xor(pmax, 32));

      // T13: rescale only if P would exceed 2^8 (never fires on sane data)
      if (!__all(pmax - m_[mi] <= 8.0f)) {
        float mnew  = fmaxf(m_[mi], pmax);
        float alpha = EXP2(m_[mi] - mnew);
        l_[mi] *= alpha;
#pragma unroll
        for (int j = 0; j < 4; ++j) {
          float aj = __shfl(alpha, hi * 4 + j);
#pragma unroll
          for (int ni = 0; ni < 4; ++ni) o[mi][ni][j] *= aj;
        }
        m_[mi] = mnew;
      }

      const float mcur = m_[mi];
      f32x4 sum4 = {};
#pragma unroll
      for (int ni = 0; ni < 4; ++ni)
#pragma unroll
        for (int r = 0; r < 4; ++r) {
          float p = EXP2(sc[ni][r] - mcur);
          sc[ni][r] = p;
          sum4[r] += p;
        }
      float rsum = (sum4[0] + sum4[1]) + (sum4[2] + sum4[3]);
      rsum += __shfl_xor(rsum, 16);
      rsum += __shfl_xor(rsum, 32);
      l_[mi] += rsum;

      // P -> per-wave LDS [q=l15][key], packed us4 (4 consecutive keys)
      unsigned short* pb = &sP[w * 2 + mi][l15 * 72];
#pragma unroll
      for (int ni = 0; ni < 4; ++ni) {
        us4 pk = { f2b(sc[ni][0]), f2b(sc[ni][1]), f2b(sc[ni][2]), f2b(sc[ni][3]) };
        *(us4*)&pb[ni * 16 + hi * 4] = pk;
      }
    }

    // O += P V
    bf16x8 pa[2][2];
#pragma unroll
    for (int mi = 0; mi < 2; ++mi) {
      pa[mi][0] = *(const bf16x8*)&sP[w * 2 + mi][l15 * 72 + hi * 8];
      pa[mi][1] = *(const bf16x8*)&sP[w * 2 + mi][l15 * 72 + 32 + hi * 8];
    }
    __builtin_amdgcn_s_setprio(1);
#pragma unroll
    for (int ni = 0; ni < 4; ++ni) {
      bf16x8 vf0 = *(const bf16x8*)&sVt[(ni * 16 + l15) * 72 + hi * 8];
      bf16x8 vf1 = *(const bf16x8*)&sVt[(ni * 16 + l15) * 72 + 32 + hi * 8];
#pragma unroll
      for (int mi = 0; mi < 2; ++mi) {
        o[mi][ni] = __builtin_amdgcn_mfma_f32_16x16x32_bf16(pa[mi][0], vf0, o[mi][ni], 0, 0, 0);
        o[mi][ni] = __builtin_amdgcn_mfma_f32_16x16x32_bf16(pa[mi][1], vf1, o[mi][ni], 0, 0, 0);
      }
    }
    __builtin_amdgcn_s_setprio(0);
  }

  const int b = bh >> 4, h = bh & 15;
#pragma unroll
  for (int mi = 0; mi < 2; ++mi) {
    float linv = 1.0f / l_[mi];
#pragma unroll
    for (int j = 0; j < 4; ++j) {
      float inv = __shfl(linv, hi * 4 + j);
      int row = qb + w * 32 + mi * 16 + hi * 4 + j;
#pragma unroll
      for (int ni = 0; ni < 4; ++ni)
        O[((size_t)b * 2048 + row) * 1024 + h * 64 + ni * 16 + l15] = f2b(o[mi][ni][j] * inv);
    }
  }
}

// ---------------------------------------------------------------------------
extern "C" void kernel_launch(void* const* d_in, const int* in_sizes, int n_in,
                              void* d_out, int out_size, void* d_ws, size_t ws_size,
                              hipStream_t stream) {
  const float* x  = (const float*)d_in[0];
  const float* Wq = (const float*)d_in[1];
  const float* Wk = (const float*)d_in[2];
  const float* Wv = (const float*)d_in[3];
  const float* Wo = (const float*)d_in[4];
  float* out = (float*)d_out;

  char* w = (char*)d_ws;
  unsigned short* xb   = (unsigned short*)(w);                       // 16 MB
  unsigned short* wqkv = (unsigned short*)(w + 16777216);            //  6 MB
  unsigned short* wo   = (unsigned short*)(w + 23068672);            //  2 MB
  unsigned short* Qb   = (unsigned short*)(w + 25165824);            // 16 MB
  unsigned short* Kb   = (unsigned short*)(w + 41943040);            // 16 MB
  unsigned short* Vtb  = (unsigned short*)(w + 58720256);            // 16 MB (V transposed)
  unsigned short* Ob   = (unsigned short*)(w + 75497472);            // 16 MB

  conv_x_kernel<<<8192, 256, 0, stream>>>(x, xb, 2097152);
  conv_wqkv_kernel<<<768, 256, 0, stream>>>(Wq, Wk, Wv, wqkv);
  conv_wo_kernel<<<256, 256, 0, stream>>>(Wo, wo);
  gemm_qkv_kernel<<<dim3(24, 64), 256, 0, stream>>>(xb, wqkv, Qb, Kb, Vtb);
  attn_kernel<<<dim3(16, 64), 256, 0, stream>>>(Qb, Kb, Vtb, Ob);
  gemm_out_kernel<<<dim3(8, 64), 256, 0, stream>>>(Ob, wo, out);
}